// Round 1
// baseline (720.119 us; speedup 1.0000x reference)
//
#include <hip/hip_runtime.h>
#include <math.h>

// DeepHeadClassifier — round 4: register-prefetched B-fragments.
// Theory: round-3 kernel was latency-bound (88% wave stall, VGPR=68 -> no
// load pipelining). Each of the 5 MFMA passes now issues ALL 32 B-fragment
// global loads into registers (issue_b) one phase ahead of its consume_gemm,
// hiding the ~250-cycle L2 latency under epilogues/softmax/LN phases.
// Occupancy is LDS-bound at 2 blocks/CU, so VGPR up to 256 is free.

#define E   256
#define NC  7
#define BM  16      // rows per block
#define TOK 48      // tokens per block
#define NT  256
#define BS  264     // LDS row stride (elements)

typedef unsigned short u16;
typedef unsigned int   u32;
typedef __attribute__((ext_vector_type(8))) short  short8;
typedef __attribute__((ext_vector_type(4))) float  f32x4;

// ws layout (bf16 elements)
#define O_IPW 0
#define O_OW  196608
#define O_GW  262144
#define O_W1  264448
#define O_W2  329984
#define CVT_TOTAL 362752

__device__ __forceinline__ float bf2f(u32 u) { return __uint_as_float(u << 16); }
__device__ __forceinline__ u16 f2bf(float f) {
    u32 u = __float_as_uint(f);
    return (u16)((u + 0x7fffu + ((u >> 16) & 1u)) >> 16);
}

__global__ void cvt_weights(const float* __restrict__ ipw, const float* __restrict__ ow,
                            const float* __restrict__ gw,  const float* __restrict__ w1,
                            const float* __restrict__ w2,  u16* __restrict__ ws) {
    int i4 = (blockIdx.x * 256 + threadIdx.x) * 4;
    if (i4 >= CVT_TOTAL) return;
    const float* src; int off;
    if      (i4 < O_OW)  { src = ipw; off = i4; }
    else if (i4 < O_GW)  { src = ow;  off = i4 - O_OW; }
    else if (i4 < O_W1)  { src = gw;  off = i4 - O_GW; }
    else if (i4 < O_W2)  { src = w1;  off = i4 - O_W1; }
    else                 { src = w2;  off = i4 - O_W2; }
    float4 v = *(const float4*)(src + off);
    ushort4 o;
    o.x = f2bf(v.x); o.y = f2bf(v.y); o.z = f2bf(v.z); o.w = f2bf(v.w);
    *(ushort4*)(ws + i4) = o;
}

// Issue ALL B-fragment loads for one GEMM pass into registers (8 ks x NTW
// n-tiles, 16 B each). Fully unrolled, static indices -> stays in VGPRs.
template<int NTW>
__device__ __forceinline__ void issue_b(const u16* __restrict__ bW, int rowBase, int lane,
                                        short8 (&b)[8][NTW]) {
    const int l16 = lane & 15, quad = lane >> 4;
    #pragma unroll
    for (int ks = 0; ks < 8; ++ks)
        #pragma unroll
        for (int j = 0; j < NTW; ++j)
            b[ks][j] = *(const short8*)(bW + (size_t)(rowBase + j * 16 + l16) * 256 + ks * 32 + quad * 8);
}

// Consume: A streamed from LDS (ds_read_b128, stride 264 -> 2-way alias = free),
// B from the prefetched register file.
template<int MT, int NTW>
__device__ __forceinline__ void consume_gemm(const u16* aLds, int aRow0, int lane,
                                             const short8 (&b)[8][NTW], f32x4 (&acc)[MT][NTW]) {
    const int l16 = lane & 15, quad = lane >> 4;
    #pragma unroll
    for (int m = 0; m < MT; ++m)
        #pragma unroll
        for (int j = 0; j < NTW; ++j) acc[m][j] = (f32x4){0.f, 0.f, 0.f, 0.f};
    #pragma unroll
    for (int ks = 0; ks < 8; ++ks) {
        short8 a[MT];
        #pragma unroll
        for (int m = 0; m < MT; ++m)
            a[m] = *(const short8*)(aLds + (size_t)(aRow0 + m * 16 + l16) * BS + ks * 32 + quad * 8);
        #pragma unroll
        for (int j = 0; j < NTW; ++j)
            #pragma unroll
            for (int m = 0; m < MT; ++m)
                acc[m][j] = __builtin_amdgcn_mfma_f32_16x16x32_bf16(a[m], b[ks][j], acc[m][j], 0, 0, 0);
    }
}

__global__ __launch_bounds__(NT, 2)
void dhc_mfma_kernel(
    const float* __restrict__ f0, const float* __restrict__ f1, const float* __restrict__ f2,
    const float* __restrict__ ipb, const float* __restrict__ ob,
    const float* __restrict__ ln1g, const float* __restrict__ ln1b,
    const float* __restrict__ gb,
    const float* __restrict__ ln2g, const float* __restrict__ ln2b,
    const float* __restrict__ b1, const float* __restrict__ b2,
    const float* __restrict__ w3, const float* __restrict__ b3,
    const u16* __restrict__ ws, float* __restrict__ d_out, int nrows)
{
    __shared__ __align__(16) u16 s_x[TOK * BS];    // stacked bf16, persists
    __shared__ __align__(16) u16 s_buf[TOK * BS];  // qk -> v/ctx -> x_res/x_ln -> fused/h0/h1/h2
    __shared__ float s_attn[BM][4][9];
    __shared__ float s_gp[BM][9];
    __shared__ float s_wgt[BM][3];
    __shared__ float s_mu[TOK], s_rstd[TOK];
    __shared__ float s_mu2[BM], s_rstd2[BM];

    const int tid  = threadIdx.x;
    const int wid  = tid >> 6, lane = tid & 63;
    const int l16  = lane & 15, quad = lane >> 4;
    const long long row0 = (long long)blockIdx.x * BM;
    const size_t fused_base = (size_t)nrows * NC;

    const u16* ipw_b = ws + O_IPW;
    const u16* ow_b  = ws + O_OW;
    const u16* gw_b  = ws + O_GW;
    const u16* w1_b  = ws + O_W1;
    const u16* w2_b  = ws + O_W2;

    short8 bq[8][4];   // prefetched B fragments (128 VGPRs), reused per pass
    short8 b5[8][2];   // w2 pass (64 VGPRs)

    // qk pass p=0 wave row bases: waves 0,1 -> q feats 0..127; waves 2,3 -> k feats 0..127
    const int rb0 = (wid < 2) ? (64 * wid) : (256 + 64 * (wid - 2));

    // ---- issue B(qk p0) before staging: L2 latency hides under P0 HBM loads ----
    issue_b<4>(ipw_b, rb0, lane, bq);

    // ---- P0: stacked fp32 -> bf16 LDS (token t = s*16+r) ----
    #pragma unroll
    for (int it = 0; it < 12; ++it) {
        int id = it * NT + tid;            // vec4 chunk over 48*256/4 = 3072
        int t  = id >> 6;                  // token
        int c4 = (id & 63) * 4;
        int s  = t >> 4, r = t & 15;
        float4 v = {0.f, 0.f, 0.f, 0.f};
        if (row0 + r < nrows) {
            const float* src = (s == 0 ? f0 : (s == 1 ? f1 : f2));
            v = *(const float4*)(src + (size_t)(row0 + r) * E + c4);
        }
        ushort4 o;
        o.x = f2bf(v.x); o.y = f2bf(v.y); o.z = f2bf(v.z); o.w = f2bf(v.w);
        *(ushort4*)(s_x + t * BS + c4) = o;
    }
    __syncthreads();

    // ---- qk passes: p=0 -> heads 0,1 ; p=1 -> heads 2,3 ----
    for (int p = 0; p < 2; ++p) {
        const int rb = rb0 + 128 * p;
        f32x4 acc[3][4];
        consume_gemm<3, 4>(s_x, 0, lane, bq, acc);
        // prefetch next pass's B: p0 -> qk p1; p1 -> v (both from in_proj)
        issue_b<4>(ipw_b, (p == 0) ? (rb0 + 128) : (512 + 64 * wid), lane, bq);
        #pragma unroll
        for (int j = 0; j < 4; ++j) {
            int n = wid * 64 + j * 16 + l16;
            float bias = ipb[rb + j * 16 + l16];
            #pragma unroll
            for (int m = 0; m < 3; ++m)
                #pragma unroll
                for (int rr = 0; rr < 4; ++rr) {
                    int tok = m * 16 + quad * 4 + rr;
                    s_buf[tok * BS + n] = f2bf(acc[m][j][rr] + bias);
                }
        }
        __syncthreads();
        // ---- P2: scores + softmax for heads 2p, 2p+1 ----
        if (tid < 96) {
            int r = tid / 6, rem = tid % 6;
            int hh = rem / 3, i = rem % 3;
            int h = 2 * p + hh;
            float d0 = 0.f, d1 = 0.f, d2 = 0.f;
            const u16* qrow = s_buf + (i * 16 + r) * BS + hh * 64;
            const u16* k0 = s_buf + (0 * 16 + r) * BS + 128 + hh * 64;
            const u16* k1 = s_buf + (1 * 16 + r) * BS + 128 + hh * 64;
            const u16* k2 = s_buf + (2 * 16 + r) * BS + 128 + hh * 64;
            for (int d8 = 0; d8 < 8; ++d8) {
                short8 qv = *(const short8*)(qrow + d8 * 8);
                short8 a0 = *(const short8*)(k0 + d8 * 8);
                short8 a1 = *(const short8*)(k1 + d8 * 8);
                short8 a2 = *(const short8*)(k2 + d8 * 8);
                #pragma unroll
                for (int e = 0; e < 8; ++e) {
                    float q = bf2f((u32)(u16)qv[e]);
                    d0 += q * bf2f((u32)(u16)a0[e]);
                    d1 += q * bf2f((u32)(u16)a1[e]);
                    d2 += q * bf2f((u32)(u16)a2[e]);
                }
            }
            d0 *= 0.125f; d1 *= 0.125f; d2 *= 0.125f;
            float mx = fmaxf(d0, fmaxf(d1, d2));
            float e0 = expf(d0 - mx), e1 = expf(d1 - mx), e2 = expf(d2 - mx);
            float inv = 1.f / (e0 + e1 + e2);
            s_attn[r][h][i * 3 + 0] = e0 * inv;
            s_attn[r][h][i * 3 + 1] = e1 * inv;
            s_attn[r][h][i * 3 + 2] = e2 * inv;
        }
        __syncthreads();
    }

    // ---- G2: v = x @ ipw[512:768]^T + b -> buf[:, 0:256) ----
    {
        const int rb = 512 + 64 * wid;
        f32x4 acc[3][4];
        consume_gemm<3, 4>(s_x, 0, lane, bq, acc);
        issue_b<4>(ow_b, 64 * wid, lane, bq);   // prefetch out_proj B
        #pragma unroll
        for (int j = 0; j < 4; ++j) {
            int n = wid * 64 + j * 16 + l16;
            float bias = ipb[rb + j * 16 + l16];
            #pragma unroll
            for (int m = 0; m < 3; ++m)
                #pragma unroll
                for (int rr = 0; rr < 4; ++rr) {
                    int tok = m * 16 + quad * 4 + rr;
                    s_buf[tok * BS + n] = f2bf(acc[m][j][rr] + bias);
                }
        }
    }
    __syncthreads();

    // ---- P4: ctx = attn (x) v, in place (thread owns (r, 16-col slice)) ----
    {
        int r = tid >> 4;
        int cb = (tid & 15) * 16;
        int h = cb >> 6;
        float a[9];
        #pragma unroll
        for (int q2 = 0; q2 < 9; ++q2) a[q2] = s_attn[r][h][q2];
        #pragma unroll
        for (int cc = 0; cc < 16; ++cc) {
            int c = cb + cc;
            float v0 = bf2f((u32)s_buf[(0 * 16 + r) * BS + c]);
            float v1 = bf2f((u32)s_buf[(1 * 16 + r) * BS + c]);
            float v2 = bf2f((u32)s_buf[(2 * 16 + r) * BS + c]);
            float c0 = a[0] * v0 + a[1] * v1 + a[2] * v2;
            float c1 = a[3] * v0 + a[4] * v1 + a[5] * v2;
            float c2 = a[6] * v0 + a[7] * v1 + a[8] * v2;
            s_buf[(0 * 16 + r) * BS + c] = f2bf(c0);
            s_buf[(1 * 16 + r) * BS + c] = f2bf(c1);
            s_buf[(2 * 16 + r) * BS + c] = f2bf(c2);
        }
    }
    __syncthreads();

    // ---- G3: att_out = ctx @ ow^T + ob; + residual -> x_res bf16 in buf ----
    {
        const int rb = 64 * wid;
        f32x4 acc[3][4];
        consume_gemm<3, 4>(s_buf, 0, lane, bq, acc);
        issue_b<4>(w1_b, 64 * wid, lane, bq);   // prefetch w1 B (covered by LN1/gate/fused/LN2)
        #pragma unroll
        for (int j = 0; j < 4; ++j) {
            int n = rb + j * 16 + l16;
            float bias = ob[n];
            #pragma unroll
            for (int m = 0; m < 3; ++m)
                #pragma unroll
                for (int rr = 0; rr < 4; ++rr) {
                    int tok = m * 16 + quad * 4 + rr;
                    acc[m][j][rr] += bias + bf2f((u32)s_x[tok * BS + n]);
                }
        }
        __syncthreads();   // all waves done reading ctx
        #pragma unroll
        for (int j = 0; j < 4; ++j) {
            int n = rb + j * 16 + l16;
            #pragma unroll
            for (int m = 0; m < 3; ++m)
                #pragma unroll
                for (int rr = 0; rr < 4; ++rr) {
                    int tok = m * 16 + quad * 4 + rr;
                    s_buf[tok * BS + n] = f2bf(acc[m][j][rr]);
                }
        }
    }
    __syncthreads();

    // ---- LN1 stats (48 tokens) ----
    if (tid < TOK) {
        const u16* xp = s_buf + tid * BS;
        float sum = 0.f, sq = 0.f;
        for (int c8 = 0; c8 < 32; ++c8) {
            short8 v = *(const short8*)(xp + c8 * 8);
            #pragma unroll
            for (int e = 0; e < 8; ++e) {
                float x = bf2f((u32)(u16)v[e]);
                sum += x; sq += x * x;
            }
        }
        float mu = sum * (1.f / 256.f);
        float var = sq * (1.f / 256.f) - mu * mu;
        s_mu[tid] = mu;
        s_rstd[tid] = rsqrtf(var + 1e-5f);
    }
    __syncthreads();
    // ---- LN1 apply in place (thread = column) ----
    {
        float g = ln1g[tid], b = ln1b[tid];
        #pragma unroll 4
        for (int t = 0; t < TOK; ++t) {
            float x = bf2f((u32)s_buf[t * BS + tid]);
            s_buf[t * BS + tid] = f2bf((x - s_mu[t]) * s_rstd[t] * g + b);
        }
    }
    __syncthreads();

    // ---- Gate: logits_g = concat(x) . gw_g  (partials over 3 segments) ----
    if (tid < 144) {
        int r = tid / 9, rem = tid % 9;
        int g = rem / 3, s = rem % 3;
        const u16* xp = s_x + (s * 16 + r) * BS;
        const u16* wp = gw_b + g * 768 + s * 256;
        float acc = 0.f;
        for (int c8 = 0; c8 < 32; ++c8) {
            short8 xv = *(const short8*)(xp + c8 * 8);
            short8 wv = *(const short8*)(wp + c8 * 8);
            #pragma unroll
            for (int e = 0; e < 8; ++e)
                acc += bf2f((u32)(u16)xv[e]) * bf2f((u32)(u16)wv[e]);
        }
        s_gp[r][g * 3 + s] = acc;
    }
    __syncthreads();
    if (tid < 48) {
        int r = tid / 3, g = tid % 3;
        s_wgt[r][g] = gb[g] + s_gp[r][g * 3 + 0] + s_gp[r][g * 3 + 1] + s_gp[r][g * 3 + 2];
    }
    __syncthreads();
    if (tid < BM) {
        float l0 = s_wgt[tid][0], l1 = s_wgt[tid][1], l2 = s_wgt[tid][2];
        float mx = fmaxf(l0, fmaxf(l1, l2));
        float e0 = expf(l0 - mx), e1 = expf(l1 - mx), e2 = expf(l2 - mx);
        float inv = 1.f / (e0 + e1 + e2);
        s_wgt[tid][0] = e0 * inv; s_wgt[tid][1] = e1 * inv; s_wgt[tid][2] = e2 * inv;
    }
    __syncthreads();

    // ---- fused = sum_s wgt*x_ln -> global fp32 + buf rows[0:16) bf16 ----
    {
        int c = tid;
        float* outF = d_out + fused_base;
        #pragma unroll 4
        for (int r = 0; r < BM; ++r) {
            float f = s_wgt[r][0] * bf2f((u32)s_buf[(0 * 16 + r) * BS + c])
                    + s_wgt[r][1] * bf2f((u32)s_buf[(1 * 16 + r) * BS + c])
                    + s_wgt[r][2] * bf2f((u32)s_buf[(2 * 16 + r) * BS + c]);
            if (row0 + r < nrows) outF[(size_t)(row0 + r) * E + c] = f;
            s_buf[r * BS + c] = f2bf(f);
        }
    }
    __syncthreads();

    // ---- LN2 stats + apply -> h0 in buf rows[0:16) ----
    if (tid < BM) {
        const u16* fp = s_buf + tid * BS;
        float sum = 0.f, sq = 0.f;
        for (int c8 = 0; c8 < 32; ++c8) {
            short8 v = *(const short8*)(fp + c8 * 8);
            #pragma unroll
            for (int e = 0; e < 8; ++e) {
                float x = bf2f((u32)(u16)v[e]);
                sum += x; sq += x * x;
            }
        }
        float mu = sum * (1.f / 256.f);
        float var = sq * (1.f / 256.f) - mu * mu;
        s_mu2[tid] = mu;
        s_rstd2[tid] = rsqrtf(var + 1e-5f);
    }
    __syncthreads();
    {
        float g = ln2g[tid], b = ln2b[tid];
        #pragma unroll
        for (int r = 0; r < BM; ++r) {
            float x = bf2f((u32)s_buf[r * BS + tid]);
            s_buf[r * BS + tid] = f2bf((x - s_mu2[r]) * s_rstd2[r] * g + b);
        }
    }
    __syncthreads();

    // ---- G4: h1 = gelu(h0 @ w1^T + b1) -> buf rows [16,32) ----
    {
        const int rb = 64 * wid;
        f32x4 acc[1][4];
        consume_gemm<1, 4>(s_buf, 0, lane, bq, acc);
        issue_b<2>(w2_b, 32 * wid, lane, b5);   // prefetch w2 B
        __syncthreads();   // all reads of h0 done before h1 writes (disjoint rows anyway)
        #pragma unroll
        for (int j = 0; j < 4; ++j) {
            int n = rb + j * 16 + l16;
            float bias = b1[n];
            #pragma unroll
            for (int rr = 0; rr < 4; ++rr) {
                int r = quad * 4 + rr;
                float x = acc[0][j][rr] + bias;
                float hgelu = 0.5f * x * (1.f + erff(x * 0.70710678118654752f));
                s_buf[(16 + r) * BS + n] = f2bf(hgelu);
            }
        }
    }
    __syncthreads();

    // ---- G5: h2 = gelu(h1 @ w2^T + b2) -> buf rows [32,48), cols [0,128) ----
    {
        const int rb = 32 * wid;
        f32x4 acc[1][2];
        consume_gemm<1, 2>(s_buf, 16, lane, b5, acc);
        __syncthreads();
        #pragma unroll
        for (int j = 0; j < 2; ++j) {
            int n = rb + j * 16 + l16;
            float bias = b2[n];
            #pragma unroll
            for (int rr = 0; rr < 4; ++rr) {
                int r = quad * 4 + rr;
                float x = acc[0][j][rr] + bias;
                float hgelu = 0.5f * x * (1.f + erff(x * 0.70710678118654752f));
                s_buf[(32 + r) * BS + n] = f2bf(hgelu);
            }
        }
    }
    __syncthreads();

    // ---- logits = h2 @ w3^T + b3 -> global fp32 ----
    if (tid < BM * NC) {
        int r = tid / NC, n = tid % NC;
        float acc = b3[n];
        const float* wr = w3 + n * 128;
        const u16* hp = s_buf + (32 + r) * BS;
        for (int k4 = 0; k4 < 32; ++k4) {
            float4 w = *(const float4*)(wr + k4 * 4);
            acc += bf2f((u32)hp[k4 * 4 + 0]) * w.x
                 + bf2f((u32)hp[k4 * 4 + 1]) * w.y
                 + bf2f((u32)hp[k4 * 4 + 2]) * w.z
                 + bf2f((u32)hp[k4 * 4 + 3]) * w.w;
        }
        if (row0 + r < nrows) d_out[(size_t)(row0 + r) * NC + n] = acc;
    }
}

extern "C" void kernel_launch(void* const* d_in, const int* in_sizes, int n_in,
                              void* d_out, int out_size, void* d_ws, size_t ws_size,
                              hipStream_t stream) {
    (void)n_in; (void)ws_size; (void)out_size;
    const int nrows = in_sizes[0] / E;
    u16* ws = (u16*)d_ws;
    cvt_weights<<<(CVT_TOTAL / 4 + 255) / 256, 256, 0, stream>>>(
        (const float*)d_in[3], (const float*)d_in[5], (const float*)d_in[9],
        (const float*)d_in[13], (const float*)d_in[15], ws);
    const int nblocks = (nrows + BM - 1) / BM;
    dhc_mfma_kernel<<<nblocks, NT, 0, stream>>>(
        (const float*)d_in[0], (const float*)d_in[1], (const float*)d_in[2],
        (const float*)d_in[4], (const float*)d_in[6],
        (const float*)d_in[7], (const float*)d_in[8],
        (const float*)d_in[10],
        (const float*)d_in[11], (const float*)d_in[12],
        (const float*)d_in[14], (const float*)d_in[16],
        (const float*)d_in[17], (const float*)d_in[18],
        ws, (float*)d_out, nrows);
}